// Round 1
// baseline (675.334 us; speedup 1.0000x reference)
//
#include <hip/hip_runtime.h>
#include <stdint.h>

#define TT   65536
#define NCH  16            // chunks per block
#define CNOM 16            // nominal chunk length
#define NBLK (TT / (NCH * CNOM))   // 256 blocks

typedef __bf16 bf16x8 __attribute__((ext_vector_type(8)));
typedef float  f32x4  __attribute__((ext_vector_type(4)));

// bf16 copies of the weights (avoid ws_size dependence)
__device__ __bf16 g_wih[768 * 256];
__device__ __bf16 g_whh[768 * 256];

__global__ void prep_w(const float* __restrict__ wih, const float* __restrict__ whh) {
  const int n = 768 * 256;
  for (int i = blockIdx.x * blockDim.x + threadIdx.x; i < n; i += gridDim.x * blockDim.x) {
    g_wih[i] = (__bf16)wih[i];
    g_whh[i] = (__bf16)whh[i];
  }
}

// Block: 512 threads = 8 waves. Block owns 16 chunks (MFMA m-dim).
// Wave w owns hidden units [32w, 32w+32): gates r,z,n for those units.
// W_hh slice register-resident (192 VGPR/lane); W_ih streamed from L2.
__global__ __launch_bounds__(512, 2) void gru_scan(
    const float* __restrict__ x, const float* __restrict__ state,
    const int* __restrict__ start, const float* __restrict__ bias,
    const float* __restrict__ bias_n, float* __restrict__ out) {
  __shared__ __align__(16) __bf16 x_s[16][264];   // +8 pad breaks bank aliasing
  __shared__ __align__(16) __bf16 h_s[16][264];
  __shared__ int s_arr[17];
  __shared__ int t_cur[16];
  __shared__ int meta_s[16];   // bit0 = active, bit1 = reset
  __shared__ int maxlen_s;

  const int tid  = threadIdx.x;
  const int w    = tid >> 6;    // wave 0..7
  const int lane = tid & 63;
  const int l15  = lane & 15;
  const int q    = lane >> 4;   // quad 0..3

  // chunk boundaries: snap nominal grid forward to next episode start
  if (tid < 17) {
    int t = (blockIdx.x * NCH + tid) * CNOM;
    if (t > 0) { while (t < TT && start[t] == 0) t++; }
    s_arr[tid] = t;
  }
  for (int i = tid; i < 16 * 264; i += 512) (&h_s[0][0])[i] = (__bf16)0.f;
  __syncthreads();
  if (tid == 0) {
    int mx = 0;
    for (int m = 0; m < 16; ++m) { int L = s_arr[m + 1] - s_arr[m]; mx = L > mx ? L : mx; }
    maxlen_s = mx;
  }
  // chunk 0 of block 0 starts from the provided initial state
  if (blockIdx.x == 0 && tid < 256) h_s[0][tid] = (__bf16)state[tid];

  // register-resident W_hh fragments: [pass][gate-class][kstep]
  bf16x8 whh[2][3][8];
#pragma unroll
  for (int p = 0; p < 2; ++p)
#pragma unroll
    for (int c = 0; c < 3; ++c) {
      const __bf16* rowp = &g_whh[(c * 256 + w * 32 + p * 16 + l15) * 256 + q * 8];
#pragma unroll
      for (int ks = 0; ks < 8; ++ks)
        whh[p][c][ks] = *(const bf16x8*)(rowp + ks * 32);
    }

  float b_r[2], b_z[2], b_in[2], b_n2[2];
#pragma unroll
  for (int p = 0; p < 2; ++p) {
    int j = w * 32 + p * 16 + l15;
    b_r[p]  = bias[j];        b_z[p]  = bias[256 + j];
    b_in[p] = bias[512 + j];  b_n2[p] = bias_n[j];
  }

  float hreg[2][4];   // fp32 mirror of this lane's h elements (D-layout)
#pragma unroll
  for (int p = 0; p < 2; ++p)
#pragma unroll
    for (int r = 0; r < 4; ++r) hreg[p][r] = 0.f;
  if (blockIdx.x == 0 && q == 0) {
#pragma unroll
    for (int p = 0; p < 2; ++p) hreg[p][0] = state[w * 32 + p * 16 + l15];
  }

  __syncthreads();
  const int ML = maxlen_s;

  for (int k = 0; k < ML; ++k) {
    // ---- step metadata ----
    if (tid < 16) {
      int t  = s_arr[tid] + k;
      int a  = (t < s_arr[tid + 1]) ? 1 : 0;
      int tc = a ? t : (TT - 1);
      int rs = a ? start[tc] : 0;
      t_cur[tid]  = tc;
      meta_s[tid] = a | (rs << 1);
    }
    __syncthreads();
    // ---- stage x rows (fp32 -> bf16 LDS) + episode reset of h ----
    {
      int m   = tid >> 5;
      int col = (tid & 31) * 8;
      const float* xr = x + (size_t)t_cur[m] * 256 + col;
      float4 a0 = *(const float4*)xr;
      float4 a1 = *(const float4*)(xr + 4);
      bf16x8 v;
      v[0] = (__bf16)a0.x; v[1] = (__bf16)a0.y; v[2] = (__bf16)a0.z; v[3] = (__bf16)a0.w;
      v[4] = (__bf16)a1.x; v[5] = (__bf16)a1.y; v[6] = (__bf16)a1.z; v[7] = (__bf16)a1.w;
      *(bf16x8*)&x_s[m][col] = v;
      if (meta_s[m] & 2) {
        bf16x8 z;
#pragma unroll
        for (int i = 0; i < 8; ++i) z[i] = (__bf16)0.f;
        *(bf16x8*)&h_s[m][col] = z;
      }
    }
#pragma unroll
    for (int r = 0; r < 4; ++r)
      if (meta_s[q * 4 + r] & 2) { hreg[0][r] = 0.f; hreg[1][r] = 0.f; }
    __syncthreads();

    // ---- MFMA + elementwise, two passes of 16 hidden units ----
#pragma unroll
    for (int p = 0; p < 2; ++p) {
      f32x4 accr = {0.f, 0.f, 0.f, 0.f};
      f32x4 accz = {0.f, 0.f, 0.f, 0.f};
      f32x4 acci = {0.f, 0.f, 0.f, 0.f};   // ig_n (x part only)
      f32x4 acch = {0.f, 0.f, 0.f, 0.f};   // hg_n (h part only)
      const int jrow = w * 32 + p * 16 + l15;
#pragma unroll
      for (int ks = 0; ks < 8; ++ks) {
        bf16x8 xf = *(const bf16x8*)&x_s[l15][ks * 32 + q * 8];
        bf16x8 hf = *(const bf16x8*)&h_s[l15][ks * 32 + q * 8];
        bf16x8 wr = *(const bf16x8*)&g_wih[(0   + jrow) * 256 + ks * 32 + q * 8];
        bf16x8 wz = *(const bf16x8*)&g_wih[(256 + jrow) * 256 + ks * 32 + q * 8];
        bf16x8 wn = *(const bf16x8*)&g_wih[(512 + jrow) * 256 + ks * 32 + q * 8];
        accr = __builtin_amdgcn_mfma_f32_16x16x32_bf16(xf, wr, accr, 0, 0, 0);
        accz = __builtin_amdgcn_mfma_f32_16x16x32_bf16(xf, wz, accz, 0, 0, 0);
        acci = __builtin_amdgcn_mfma_f32_16x16x32_bf16(xf, wn, acci, 0, 0, 0);
        accr = __builtin_amdgcn_mfma_f32_16x16x32_bf16(hf, whh[p][0][ks], accr, 0, 0, 0);
        accz = __builtin_amdgcn_mfma_f32_16x16x32_bf16(hf, whh[p][1][ks], accz, 0, 0, 0);
        acch = __builtin_amdgcn_mfma_f32_16x16x32_bf16(hf, whh[p][2][ks], acch, 0, 0, 0);
      }
#pragma unroll
      for (int r = 0; r < 4; ++r) {
        int m = q * 4 + r;
        float rp = accr[r] + b_r[p];
        float zp = accz[r] + b_z[p];
        float rg = 1.f / (1.f + __expf(-rp));
        float zg = 1.f / (1.f + __expf(-zp));
        float np = acci[r] + b_in[p] + rg * (acch[r] + b_n2[p]);
        np = fminf(fmaxf(np, -30.f), 30.f);
        float e2 = __expf(2.f * np);
        float ng = (e2 - 1.f) / (e2 + 1.f);
        float hn = ng + zg * (hreg[p][r] - ng);
        if (meta_s[m] & 1) {
          hreg[p][r] = hn;
          out[(size_t)t_cur[m] * 256 + (w * 32 + p * 16 + l15)] = hn;
        }
      }
    }
    __syncthreads();   // all waves done reading h_s before updates land
#pragma unroll
    for (int p = 0; p < 2; ++p)
#pragma unroll
      for (int r = 0; r < 4; ++r) {
        int m = q * 4 + r;
        if (meta_s[m] & 1) h_s[m][w * 32 + p * 16 + l15] = (__bf16)hreg[p][r];
      }
    __syncthreads();   // h_s stable before next step's meta/stage phase
  }
}

__global__ void fin_copy(float* __restrict__ out) {
  int i = threadIdx.x;
  out[(size_t)TT * 256 + i] = out[((size_t)TT - 1) * 256 + i];
}

extern "C" void kernel_launch(void* const* d_in, const int* in_sizes, int n_in,
                              void* d_out, int out_size, void* d_ws, size_t ws_size,
                              hipStream_t stream) {
  const float* x      = (const float*)d_in[0];
  const float* state  = (const float*)d_in[1];
  const int*   start  = (const int*)d_in[2];
  // d_in[3] = next_done (unused)
  const float* wih    = (const float*)d_in[4];
  const float* whh    = (const float*)d_in[5];
  const float* bias   = (const float*)d_in[6];
  const float* bias_n = (const float*)d_in[7];
  float* out = (float*)d_out;

  prep_w<<<256, 256, 0, stream>>>(wih, whh);
  gru_scan<<<NBLK, 512, 0, stream>>>(x, state, start, bias, bias_n, out);
  fin_copy<<<1, 256, 0, stream>>>(out);
}

// Round 2
// 352.164 us; speedup vs baseline: 1.9177x; 1.9177x over previous
//
#include <hip/hip_runtime.h>
#include <hip/hip_bf16.h>
#include <stdint.h>

#define TT   65536
#define NCH  16
#define CNOM 16
#define NBLK 256   // scan blocks

typedef __bf16 bf16x8 __attribute__((ext_vector_type(8)));
typedef float  f32x4  __attribute__((ext_vector_type(4)));

__device__ __bf16 g_wih[768 * 256];
__device__ __bf16 g_whh[768 * 256];
__device__ __bf16 g_xbf[TT * 256];
__device__ __bf16 g_ig[(size_t)TT * 768];

__device__ __forceinline__ void gl_lds16(const void* g, void* l) {
  __builtin_amdgcn_global_load_lds(
      (const __attribute__((address_space(1))) void*)(unsigned long long)(uintptr_t)g,
      (__attribute__((address_space(3))) void*)(unsigned int)(uintptr_t)l,
      16, 0, 0);
}

__global__ void prep_w(const float* __restrict__ wih, const float* __restrict__ whh) {
  const int n = 768 * 256;
  for (int i = blockIdx.x * blockDim.x + threadIdx.x; i < n; i += gridDim.x * blockDim.x) {
    g_wih[i] = (__bf16)wih[i];
    g_whh[i] = (__bf16)whh[i];
  }
}

__global__ void prep_x(const float* __restrict__ x) {
  int i = (blockIdx.x * 256 + threadIdx.x) * 8;
  float4 a0 = *(const float4*)(x + i);
  float4 a1 = *(const float4*)(x + i + 4);
  bf16x8 v;
  v[0] = (__bf16)a0.x; v[1] = (__bf16)a0.y; v[2] = (__bf16)a0.z; v[3] = (__bf16)a0.w;
  v[4] = (__bf16)a1.x; v[5] = (__bf16)a1.y; v[6] = (__bf16)a1.z; v[7] = (__bf16)a1.w;
  *(bf16x8*)(g_xbf + i) = v;
}

// ---- phase 1: igates[t][768] = x @ W_ih^T + bias, bf16 out ----
// grid 3072 = 512 m-tiles x 6 n-tiles; 128x128 tile, BK=64, XOR-swizzled LDS.
__global__ __launch_bounds__(256) void gemm_ig(const float* __restrict__ bias) {
  __shared__ __align__(16) __bf16 a_s[128 * 64];
  __shared__ __align__(16) __bf16 b_s[128 * 64];
  const int tid = threadIdx.x;
  const int w = tid >> 6, lane = tid & 63, l15 = lane & 15, q = lane >> 4;
  const int mt = blockIdx.x / 6, nt = blockIdx.x - mt * 6;
  const int m0 = mt * 128, n0 = nt * 128;
  const int wm = w >> 1, wn = w & 1;

  f32x4 acc[4][4];
#pragma unroll
  for (int a = 0; a < 4; ++a)
#pragma unroll
    for (int b = 0; b < 4; ++b) acc[a][b] = (f32x4){0.f, 0.f, 0.f, 0.f};

  for (int kc = 0; kc < 4; ++kc) {
#pragma unroll
    for (int i = 0; i < 4; ++i) {
      int pslot = i * 256 + tid;
      int row = pslot >> 3, cb = (pslot & 7) ^ (row & 7);
      gl_lds16((const char*)g_xbf + ((size_t)(m0 + row) * 256 + kc * 64) * 2 + cb * 16,
               (char*)a_s + (i * 256 + (tid & ~63)) * 16);
      gl_lds16((const char*)g_wih + ((size_t)(n0 + row) * 256 + kc * 64) * 2 + cb * 16,
               (char*)b_s + (i * 256 + (tid & ~63)) * 16);
    }
    __syncthreads();
#pragma unroll
    for (int ks = 0; ks < 2; ++ks) {
      bf16x8 af[4], bfr[4];
#pragma unroll
      for (int tm = 0; tm < 4; ++tm) {
        int row = wm * 64 + tm * 16 + l15;
        int cb = (ks * 4 + q) ^ (row & 7);
        af[tm] = *(const bf16x8*)((const char*)a_s + row * 128 + cb * 16);
      }
#pragma unroll
      for (int tn = 0; tn < 4; ++tn) {
        int row = wn * 64 + tn * 16 + l15;
        int cb = (ks * 4 + q) ^ (row & 7);
        bfr[tn] = *(const bf16x8*)((const char*)b_s + row * 128 + cb * 16);
      }
#pragma unroll
      for (int tm = 0; tm < 4; ++tm)
#pragma unroll
        for (int tn = 0; tn < 4; ++tn)
          acc[tm][tn] = __builtin_amdgcn_mfma_f32_16x16x32_bf16(af[tm], bfr[tn], acc[tm][tn], 0, 0, 0);
    }
    __syncthreads();
  }
  float bv[4];
#pragma unroll
  for (int tn = 0; tn < 4; ++tn) bv[tn] = bias[n0 + wn * 64 + tn * 16 + l15];
#pragma unroll
  for (int tm = 0; tm < 4; ++tm) {
    int rowb = m0 + wm * 64 + tm * 16 + q * 4;
#pragma unroll
    for (int tn = 0; tn < 4; ++tn) {
      int col = n0 + wn * 64 + tn * 16 + l15;
      __bf16* op = g_ig + (size_t)rowb * 768 + col;
#pragma unroll
      for (int r = 0; r < 4; ++r) op[(size_t)r * 768] = (__bf16)(acc[tm][tn][r] + bv[tn]);
    }
  }
}

// ---- phase 2: the scan. W_hh register-resident; igates async-prefetched. ----
__global__ __launch_bounds__(512, 2) void gru_scan(
    const float* __restrict__ state, const int* __restrict__ start,
    const float* __restrict__ bias_n, float* __restrict__ out) {
  __shared__ __align__(16) __bf16 h_s[16][264];
  __shared__ __align__(16) __bf16 ig_s[2][16 * 768];
  __shared__ int s_arr[17];

  const int tid = threadIdx.x;
  const int w = tid >> 6, lane = tid & 63, l15 = lane & 15, q = lane >> 4;
  const int jrow0 = w * 32 + l15;

  if (tid < 17) {
    int t = (blockIdx.x * NCH + tid) * CNOM;
    if (t > 0) { while (t < TT && start[t] == 0) t++; }
    s_arr[tid] = t;
  }
  for (int i = tid; i < 16 * 264; i += 512) (&h_s[0][0])[i] = (__bf16)0.f;
  __syncthreads();

  int sa[4], len[4];
#pragma unroll
  for (int r = 0; r < 4; ++r) {
    sa[r] = s_arr[q * 4 + r];
    len[r] = s_arr[q * 4 + r + 1] - sa[r];
  }
  int ML = 0;
  for (int m = 0; m < 16; ++m) { int L = s_arr[m + 1] - s_arr[m]; ML = L > ML ? L : ML; }

  int ig_off[3], ig_sm[3];
#pragma unroll
  for (int i = 0; i < 3; ++i) {
    int sB = (i * 512 + tid) * 16;
    int m = sB / 1536;
    ig_off[i] = sB - m * 1536;
    ig_sm[i] = s_arr[m];
  }

  float hreg[2][4];
#pragma unroll
  for (int p = 0; p < 2; ++p)
#pragma unroll
    for (int r = 0; r < 4; ++r) hreg[p][r] = 0.f;

  const int start0 = start[0];
  if (blockIdx.x == 0) {
    if (tid < 256) h_s[0][tid] = start0 ? (__bf16)0.f : (__bf16)state[tid];
    if (q == 0 && !start0) {
      hreg[0][0] = state[jrow0];
      hreg[1][0] = state[jrow0 + 16];
    }
  }

  // prologue: igates for k=0 into buf 0
#pragma unroll
  for (int i = 0; i < 3; ++i) {
    int t = ig_sm[i]; if (t > TT - 1) t = TT - 1;
    gl_lds16((const char*)g_ig + (size_t)t * 1536 + ig_off[i],
             (char*)&ig_s[0][0] + (i * 512 + (tid & ~63)) * 16);
  }

  // register-resident W_hh: [pass p][gate c][ks]
  bf16x8 whh[2][3][8];
#pragma unroll
  for (int p = 0; p < 2; ++p)
#pragma unroll
    for (int c = 0; c < 3; ++c) {
      const __bf16* rp = &g_whh[(c * 256 + w * 32 + p * 16 + l15) * 256 + q * 8];
#pragma unroll
      for (int ks = 0; ks < 8; ++ks) whh[p][c][ks] = *(const bf16x8*)(rp + ks * 32);
    }
  const float bn2[2] = { bias_n[jrow0], bias_n[jrow0 + 16] };
  __syncthreads();

  for (int k = 0; k < ML; ++k) {
    const int bc = k & 1;
    // prefetch igates(k+1) -> other buffer (async, drains at first barrier)
#pragma unroll
    for (int i = 0; i < 3; ++i) {
      int t = ig_sm[i] + k + 1; if (t > TT - 1) t = TT - 1;
      gl_lds16((const char*)g_ig + (size_t)t * 1536 + ig_off[i],
               (char*)&ig_s[bc ^ 1][0] + (i * 512 + (tid & ~63)) * 16);
    }
    int fnext[4];
#pragma unroll
    for (int r = 0; r < 4; ++r) {
      int t = sa[r] + k + 1; if (t > TT - 1) t = TT - 1;
      fnext[r] = start[t];
    }

    const __bf16* igS = &ig_s[bc][0];
#pragma unroll
    for (int p = 0; p < 2; ++p) {
      f32x4 ar = {0.f,0.f,0.f,0.f}, az = {0.f,0.f,0.f,0.f}, ah = {0.f,0.f,0.f,0.f};
#pragma unroll
      for (int ks = 0; ks < 8; ++ks) {
        bf16x8 hf = *(const bf16x8*)&h_s[l15][ks * 32 + q * 8];
        ar = __builtin_amdgcn_mfma_f32_16x16x32_bf16(hf, whh[p][0][ks], ar, 0, 0, 0);
        az = __builtin_amdgcn_mfma_f32_16x16x32_bf16(hf, whh[p][1][ks], az, 0, 0, 0);
        ah = __builtin_amdgcn_mfma_f32_16x16x32_bf16(hf, whh[p][2][ks], ah, 0, 0, 0);
      }
      const int j = jrow0 + p * 16;
#pragma unroll
      for (int r = 0; r < 4; ++r) {
        int m = q * 4 + r;
        float igr = (float)igS[m * 768 + j];
        float igz = (float)igS[m * 768 + 256 + j];
        float ign = (float)igS[m * 768 + 512 + j];
        float rp = ar[r] + igr, zp = az[r] + igz;
        float rg = 1.f / (1.f + __expf(-rp));
        float zg = 1.f / (1.f + __expf(-zp));
        float np = ign + rg * (ah[r] + bn2[p]);
        np = fminf(fmaxf(np, -30.f), 30.f);
        float e2 = __expf(2.f * np);
        float ng = (e2 - 1.f) / (e2 + 1.f);
        float hn = ng + zg * (hreg[p][r] - ng);
        if (k < len[r]) out[(size_t)(sa[r] + k) * 256 + j] = hn;
        hreg[p][r] = fnext[r] ? 0.f : hn;
      }
    }
    __syncthreads();   // all h_s reads + ig_s[bc] reads done
#pragma unroll
    for (int p = 0; p < 2; ++p)
#pragma unroll
      for (int r = 0; r < 4; ++r)
        h_s[q * 4 + r][jrow0 + p * 16] = (__bf16)hreg[p][r];
    __syncthreads();   // h_s visible for next step
  }
}

__global__ void fin_copy(float* __restrict__ out) {
  int i = threadIdx.x;
  out[(size_t)TT * 256 + i] = out[((size_t)TT - 1) * 256 + i];
}

extern "C" void kernel_launch(void* const* d_in, const int* in_sizes, int n_in,
                              void* d_out, int out_size, void* d_ws, size_t ws_size,
                              hipStream_t stream) {
  const float* x      = (const float*)d_in[0];
  const float* state  = (const float*)d_in[1];
  const int*   start  = (const int*)d_in[2];
  const float* wih    = (const float*)d_in[4];
  const float* whh    = (const float*)d_in[5];
  const float* bias   = (const float*)d_in[6];
  const float* bias_n = (const float*)d_in[7];
  float* out = (float*)d_out;

  prep_w<<<256, 256, 0, stream>>>(wih, whh);
  prep_x<<<8192, 256, 0, stream>>>(x);
  gemm_ig<<<3072, 256, 0, stream>>>(bias);
  gru_scan<<<NBLK, 512, 0, stream>>>(state, start, bias_n, out);
  fin_copy<<<1, 256, 0, stream>>>(out);
}